// Round 1
// baseline (1334.743 us; speedup 1.0000x reference)
//
#include <hip/hip_runtime.h>
#include <math.h>

#define B_DIM 4
#define F_DIM 512
#define T_DIM 2048
#define H_DIM 4
#define HF    128

__device__ __forceinline__ float dot4(float4 a, float4 b) {
    return a.x*b.x + a.y*b.y + a.z*b.z + a.w*b.w;
}

// ---------------- Kernel 1: QKV GEMM + bias + RoPE epilogue ----------------
// Computes Out[b][h][t][j] (layout [B][H][T][128]) for Q', K' (rope applied), V.
// blockIdx.z = b*3 + which (0=Q,1=K,2=V); tile: 64 t-rows x 64 fo-cols, BK=16.
__global__ __launch_bounds__(256)
void qkv_rope_kernel(const float* __restrict__ x,
                     const float* __restrict__ Wq, const float* __restrict__ bq,
                     const float* __restrict__ Wk, const float* __restrict__ bk,
                     const float* __restrict__ Wv, const float* __restrict__ bv,
                     float* __restrict__ Qp, float* __restrict__ Kp, float* __restrict__ Vp)
{
    const int b     = blockIdx.z / 3;
    const int which = blockIdx.z % 3;
    const float* __restrict__ W   = (which == 0) ? Wq : (which == 1) ? Wk : Wv;
    const float* __restrict__ bia = (which == 0) ? bq : (which == 1) ? bk : bv;
    float* __restrict__ Out       = (which == 0) ? Qp : (which == 1) ? Kp : Vp;

    const int t0  = blockIdx.x * 64;
    const int fo0 = blockIdx.y * 64;

    __shared__ float As[16][65];   // [k][t]  (+1 pad)
    __shared__ float Bs[16][65];   // [k][fo] (+1 pad)

    const int tid = threadIdx.x;
    const int tx  = tid & 15;
    const int ty  = tid >> 4;

    float acc[4][4] = {};

    const float* __restrict__ xb = x + (size_t)b * F_DIM * T_DIM;

    for (int f0 = 0; f0 < F_DIM; f0 += 16) {
        {   // stage X[f][t] tile: 16 x 64, coalesced float4 along t
            const int fl = tid >> 4;
            const int tl = (tid & 15) << 2;
            const float4 v = *(const float4*)(xb + (size_t)(f0 + fl) * T_DIM + t0 + tl);
            As[fl][tl+0] = v.x; As[fl][tl+1] = v.y; As[fl][tl+2] = v.z; As[fl][tl+3] = v.w;
        }
        {   // stage W[fo][f] tile transposed into Bs[k][n]
            const int n  = tid >> 2;
            const int k4 = (tid & 3) << 2;
            const float4 v = *(const float4*)(W + (size_t)(fo0 + n) * F_DIM + f0 + k4);
            Bs[k4+0][n] = v.x; Bs[k4+1][n] = v.y; Bs[k4+2][n] = v.z; Bs[k4+3][n] = v.w;
        }
        __syncthreads();
        #pragma unroll
        for (int k = 0; k < 16; ++k) {
            float a[4], bb[4];
            #pragma unroll
            for (int i = 0; i < 4; ++i) a[i]  = As[k][ty + 16*i];
            #pragma unroll
            for (int j = 0; j < 4; ++j) bb[j] = Bs[k][tx + 16*j];
            #pragma unroll
            for (int i = 0; i < 4; ++i)
                #pragma unroll
                for (int j = 0; j < 4; ++j)
                    acc[i][j] += a[i] * bb[j];
        }
        __syncthreads();
    }

    // Epilogue: bias + rope. A 64-wide fo-tile covers exactly one rope pair-group
    // (chunks 0,1 or 2,3) of one head. Thread cols tx+{0,16,32,48}: cols (0,2)
    // and (1,3) are rope partners (32 apart) -> both held by this thread.
    const int h     = fo0 / HF;
    const int jbase = fo0 % HF;     // 0 (chunks 0,1) or 64 (chunks 2,3)
    float* __restrict__ OutB = Out + ((size_t)b * H_DIM + h) * T_DIM * HF;

    float bv4[4];
    #pragma unroll
    for (int j = 0; j < 4; ++j) bv4[j] = bia[fo0 + tx + 16*j];

    #pragma unroll
    for (int i = 0; i < 4; ++i) {
        const int t = t0 + ty + 16*i;
        const float v0 = acc[i][0] + bv4[0];
        const float v1 = acc[i][1] + bv4[1];
        const float v2 = acc[i][2] + bv4[2];
        const float v3 = acc[i][3] + bv4[3];
        float* rowp = OutB + (size_t)t * HF + jbase;
        if (which < 2) {
            #pragma unroll
            for (int pr = 0; pr < 2; ++pr) {
                const int wi = tx + 16*pr;                       // 0..31
                const float u = ldexpf((float)t, -wi) * 0.0625f; // t * 2^-wi / 16 (exact)
                float sn, cs;
                sincosf(u, &sn, &cs);
                const float r  = (pr == 0) ? v0 : v1;
                const float im = (pr == 0) ? v2 : v3;
                rowp[wi]      = r * sn - im * cs;  // rot: (r*Ur - i*Ui, ...) Ur=sin
                rowp[wi + 32] = r * cs + im * sn;
            }
        } else {
            rowp[tx +  0] = v0;
            rowp[tx + 16] = v1;
            rowp[tx + 32] = v2;
            rowp[tx + 48] = v3;
        }
    }
}

// ---------------- Kernel 2: dual-softmax flash attention + residual ----------------
// Q',K',V layout [B][H][T][128]; features [0,64)=softmax1, [64,128)=softmax2 inputs.
// QT=KT=32. 256 threads: rg=tid>>4 owns q-rows {rg, rg+16}; sub=tid&15 owns
// k-cols {sub, sub+16} in scores and j-slice {4sub..4sub+3, 64+4sub..} in PV.
#define QT 32
#define KT 32
#define LSTR 132

__global__ __launch_bounds__(256)
void attn_kernel(const float* __restrict__ Qp, const float* __restrict__ Kp,
                 const float* __restrict__ Vp, const float* __restrict__ x,
                 const float* __restrict__ s2g, float* __restrict__ out)
{
    const int q0 = blockIdx.x * QT;
    const int h  = blockIdx.y;
    const int b  = blockIdx.z;

    __shared__ float  Qs[QT][LSTR];
    __shared__ float  Ks[KT][LSTR];
    __shared__ float  Vs[KT][LSTR];
    __shared__ float2 Pp[QT][36];   // {p1,p2} per (q,k)

    const int tid = threadIdx.x;
    const int rg  = tid >> 4;   // 0..15
    const int sub = tid & 15;   // 0..15

    const size_t bh = ((size_t)b * H_DIM + h) * T_DIM;
    const float* __restrict__ Qb = Qp + (bh + q0) * HF;
    const float* __restrict__ Kb = Kp + bh * HF;
    const float* __restrict__ Vb = Vp + bh * HF;

    for (int i = tid; i < QT * (HF/4); i += 256) {
        const int r = i >> 5;
        const int c = (i & 31) << 2;
        *(float4*)&Qs[r][c] = *(const float4*)(Qb + (size_t)r * HF + c);
    }

    float m1[2] = {-1e30f, -1e30f}, m2[2] = {-1e30f, -1e30f};
    float l1[2] = {0.f, 0.f},       l2[2] = {0.f, 0.f};
    float O1[2][8] = {}, O2[2][8] = {};

    for (int k0 = 0; k0 < T_DIM; k0 += KT) {
        __syncthreads();   // prev-iter Vs/Pp reads done before restaging
        for (int i = tid; i < KT * (HF/4); i += 256) {
            const int r = i >> 5;
            const int c = (i & 31) << 2;
            *(float4*)&Ks[r][c] = *(const float4*)(Kb + (size_t)(k0 + r) * HF + c);
            *(float4*)&Vs[r][c] = *(const float4*)(Vb + (size_t)(k0 + r) * HF + c);
        }
        __syncthreads();

        // ---- scores: s{row}{kcol}{a=softmax1,b=softmax2} ----
        float s00a=0.f, s00b=0.f, s01a=0.f, s01b=0.f;
        float s10a=0.f, s10b=0.f, s11a=0.f, s11b=0.f;
        #pragma unroll 4
        for (int j = 0; j < 64; j += 4) {
            const float4 q0a = *(const float4*)&Qs[rg][j];
            const float4 q0b = *(const float4*)&Qs[rg][64+j];
            const float4 q1a = *(const float4*)&Qs[rg+16][j];
            const float4 q1b = *(const float4*)&Qs[rg+16][64+j];
            const float4 k0a = *(const float4*)&Ks[sub][j];
            const float4 k0b = *(const float4*)&Ks[sub][64+j];
            const float4 k1a = *(const float4*)&Ks[sub+16][j];
            const float4 k1b = *(const float4*)&Ks[sub+16][64+j];
            s00a += dot4(q0a,k0a); s00b += dot4(q0b,k0b);
            s01a += dot4(q0a,k1a); s01b += dot4(q0b,k1b);
            s10a += dot4(q1a,k0a); s10b += dot4(q1b,k0b);
            s11a += dot4(q1a,k1a); s11b += dot4(q1b,k1b);
        }
        const float sc = 0.0625f;  // 1/sqrt(F/2) = 1/16
        s00a*=sc; s00b*=sc; s01a*=sc; s01b*=sc;
        s10a*=sc; s10b*=sc; s11a*=sc; s11b*=sc;

        // ---- dual online softmax per row ----
        #pragma unroll
        for (int r = 0; r < 2; ++r) {
            const float sa0 = r ? s10a : s00a;
            const float sa1 = r ? s11a : s01a;
            const float sb0 = r ? s10b : s00b;
            const float sb1 = r ? s11b : s01b;
            float mxa = fmaxf(sa0, sa1);
            float mxb = fmaxf(sb0, sb1);
            #pragma unroll
            for (int d = 1; d < 16; d <<= 1) {
                mxa = fmaxf(mxa, __shfl_xor(mxa, d, 16));
                mxb = fmaxf(mxb, __shfl_xor(mxb, d, 16));
            }
            const float mna = fmaxf(m1[r], mxa);
            const float mnb = fmaxf(m2[r], mxb);
            const float ala = expf(m1[r] - mna);
            const float alb = expf(m2[r] - mnb);
            const float pa0 = expf(sa0 - mna);
            const float pa1 = expf(sa1 - mna);
            const float pb0 = expf(sb0 - mnb);
            const float pb1 = expf(sb1 - mnb);
            float suma = pa0 + pa1;
            float sumb = pb0 + pb1;
            #pragma unroll
            for (int d = 1; d < 16; d <<= 1) {
                suma += __shfl_xor(suma, d, 16);
                sumb += __shfl_xor(sumb, d, 16);
            }
            l1[r] = l1[r] * ala + suma;  m1[r] = mna;
            l2[r] = l2[r] * alb + sumb;  m2[r] = mnb;
            #pragma unroll
            for (int e = 0; e < 8; ++e) { O1[r][e] *= ala; O2[r][e] *= alb; }
            Pp[rg + 16*r][sub]      = make_float2(pa0, pb0);
            Pp[rg + 16*r][sub + 16] = make_float2(pa1, pb1);
        }
        __syncthreads();

        // ---- PV accumulate ----
        #pragma unroll 2
        for (int ki = 0; ki < KT; ++ki) {
            const float4 va = *(const float4*)&Vs[ki][4*sub];
            const float4 vb = *(const float4*)&Vs[ki][64 + 4*sub];
            #pragma unroll
            for (int r = 0; r < 2; ++r) {
                const float2 p = Pp[rg + 16*r][ki];
                O1[r][0] += p.x * va.x; O1[r][1] += p.x * va.y;
                O1[r][2] += p.x * va.z; O1[r][3] += p.x * va.w;
                O1[r][4] += p.x * vb.x; O1[r][5] += p.x * vb.y;
                O1[r][6] += p.x * vb.z; O1[r][7] += p.x * vb.w;
                O2[r][0] += p.y * va.x; O2[r][1] += p.y * va.y;
                O2[r][2] += p.y * va.z; O2[r][3] += p.y * va.w;
                O2[r][4] += p.y * vb.x; O2[r][5] += p.y * vb.y;
                O2[r][6] += p.y * vb.z; O2[r][7] += p.y * vb.w;
            }
        }
    }

    // ---- epilogue: A = A1 - s2[h]*A2, residual, write [B][F][T] ----
    const float s2h = s2g[h];
    #pragma unroll
    for (int r = 0; r < 2; ++r) {
        const int t = q0 + rg + 16*r;
        const float i1 = 1.0f / l1[r];
        const float i2 = s2h / l2[r];
        const size_t base = (size_t)b * F_DIM * T_DIM + t;
        #pragma unroll
        for (int e = 0; e < 8; ++e) {
            const int j = (e < 4) ? (4*sub + e) : (64 + 4*sub + (e - 4));
            const size_t idx = base + (size_t)(h * HF + j) * T_DIM;
            out[idx] = x[idx] + O1[r][e] * i1 - O2[r][e] * i2;
        }
    }
}

extern "C" void kernel_launch(void* const* d_in, const int* in_sizes, int n_in,
                              void* d_out, int out_size, void* d_ws, size_t ws_size,
                              hipStream_t stream)
{
    const float* x  = (const float*)d_in[0];
    const float* Wq = (const float*)d_in[1];
    const float* bq = (const float*)d_in[2];
    const float* Wk = (const float*)d_in[3];
    const float* bk = (const float*)d_in[4];
    const float* Wv = (const float*)d_in[5];
    const float* bv = (const float*)d_in[6];
    const float* s2 = (const float*)d_in[7];
    float* out = (float*)d_out;

    const size_t per = (size_t)B_DIM * H_DIM * T_DIM * HF;  // 4M floats = 16 MB
    float* Qp = (float*)d_ws;
    float* Kp = Qp + per;
    float* Vp = Kp + per;   // total 48 MB of workspace

    dim3 g1(T_DIM/64, F_DIM/64, B_DIM*3);
    hipLaunchKernelGGL(qkv_rope_kernel, g1, dim3(256), 0, stream,
                       x, Wq, bq, Wk, bk, Wv, bv, Qp, Kp, Vp);

    dim3 g2(T_DIM/QT, H_DIM, B_DIM);
    hipLaunchKernelGGL(attn_kernel, g2, dim3(256), 0, stream,
                       Qp, Kp, Vp, x, s2, out);
}

// Round 2
// 482.705 us; speedup vs baseline: 2.7651x; 2.7651x over previous
//
#include <hip/hip_runtime.h>
#include <math.h>

#define B_DIM 4
#define F_DIM 512
#define T_DIM 2048
#define H_DIM 4
#define HF    128

typedef __attribute__((ext_vector_type(8))) short short8;
typedef __attribute__((ext_vector_type(4))) float floatx4;

__device__ __forceinline__ unsigned short f2bf(float f) {
    unsigned u = __float_as_uint(f);
    u += 0x7FFF + ((u >> 16) & 1);   // RNE
    return (unsigned short)(u >> 16);
}

__device__ __forceinline__ float dot4(float4 a, float4 b) {
    return a.x*b.x + a.y*b.y + a.z*b.z + a.w*b.w;
}

// ---------------- Kernel 1: QKV GEMM (fp32) + bias + RoPE, bf16 outputs ----
// Q', K' -> bf16 [B][H][T][128].  V -> bf16 TRANSPOSED [B][H][128][T]
// (so the attention kernel's PV B-operand is contiguous along kcol in LDS).
__global__ __launch_bounds__(256)
void qkv_rope_kernel(const float* __restrict__ x,
                     const float* __restrict__ Wq, const float* __restrict__ bq,
                     const float* __restrict__ Wk, const float* __restrict__ bk,
                     const float* __restrict__ Wv, const float* __restrict__ bv,
                     unsigned short* __restrict__ Qb, unsigned short* __restrict__ Kb,
                     unsigned short* __restrict__ Vtb)
{
    const int b     = blockIdx.z / 3;
    const int which = blockIdx.z % 3;
    const float* __restrict__ W   = (which == 0) ? Wq : (which == 1) ? Wk : Wv;
    const float* __restrict__ bia = (which == 0) ? bq : (which == 1) ? bk : bv;

    const int t0  = blockIdx.x * 64;
    const int fo0 = blockIdx.y * 64;

    __shared__ float As[16][65];
    __shared__ float Bs[16][65];

    const int tid = threadIdx.x;
    const int tx  = tid & 15;
    const int ty  = tid >> 4;

    float acc[4][4] = {};
    const float* __restrict__ xb = x + (size_t)b * F_DIM * T_DIM;

    for (int f0 = 0; f0 < F_DIM; f0 += 16) {
        {
            const int fl = tid >> 4;
            const int tl = (tid & 15) << 2;
            const float4 v = *(const float4*)(xb + (size_t)(f0 + fl) * T_DIM + t0 + tl);
            As[fl][tl+0] = v.x; As[fl][tl+1] = v.y; As[fl][tl+2] = v.z; As[fl][tl+3] = v.w;
        }
        {
            const int n  = tid >> 2;
            const int k4 = (tid & 3) << 2;
            const float4 v = *(const float4*)(W + (size_t)(fo0 + n) * F_DIM + f0 + k4);
            Bs[k4+0][n] = v.x; Bs[k4+1][n] = v.y; Bs[k4+2][n] = v.z; Bs[k4+3][n] = v.w;
        }
        __syncthreads();
        #pragma unroll
        for (int k = 0; k < 16; ++k) {
            float a[4], bb[4];
            #pragma unroll
            for (int i = 0; i < 4; ++i) a[i]  = As[k][ty + 16*i];
            #pragma unroll
            for (int j = 0; j < 4; ++j) bb[j] = Bs[k][tx + 16*j];
            #pragma unroll
            for (int i = 0; i < 4; ++i)
                #pragma unroll
                for (int j = 0; j < 4; ++j)
                    acc[i][j] += a[i] * bb[j];
        }
        __syncthreads();
    }

    const int h     = fo0 / HF;
    const int jbase = fo0 % HF;     // 0 or 64
    const size_t bh = (size_t)b * H_DIM + h;

    float bv4[4];
    #pragma unroll
    for (int j = 0; j < 4; ++j) bv4[j] = bia[fo0 + tx + 16*j];

    if (which < 2) {
        unsigned short* __restrict__ OutB =
            ((which == 0) ? Qb : Kb) + bh * T_DIM * HF;
        #pragma unroll
        for (int i = 0; i < 4; ++i) {
            const int t = t0 + ty + 16*i;
            const float v0 = acc[i][0] + bv4[0];
            const float v1 = acc[i][1] + bv4[1];
            const float v2 = acc[i][2] + bv4[2];
            const float v3 = acc[i][3] + bv4[3];
            unsigned short* rowp = OutB + (size_t)t * HF + jbase;
            #pragma unroll
            for (int pr = 0; pr < 2; ++pr) {
                const int wi = tx + 16*pr;                       // 0..31
                const float u = ldexpf((float)t, -wi) * 0.0625f;
                float sn, cs;
                sincosf(u, &sn, &cs);
                const float r  = (pr == 0) ? v0 : v1;
                const float im = (pr == 0) ? v2 : v3;
                rowp[wi]      = f2bf(r * sn - im * cs);
                rowp[wi + 32] = f2bf(r * cs + im * sn);
            }
        }
    } else {
        // V transposed: Vt[b][h][feat][t]
        unsigned short* __restrict__ VtB = Vtb + (bh * HF + jbase) * T_DIM;
        #pragma unroll
        for (int i = 0; i < 4; ++i) {
            const int t = t0 + ty + 16*i;
            #pragma unroll
            for (int j = 0; j < 4; ++j)
                VtB[(size_t)(tx + 16*j) * T_DIM + t] = f2bf(acc[i][j] + bv4[j]);
        }
    }
}

// ---------------- Kernel 2: MFMA flash attention (dual softmax) ------------
// Block: 256 threads = 4 waves; wave w owns q-rows [q0+16w, q0+16w+16).
// QT=64, KT=64. Features [0,64)=softmax1, [64,128)=softmax2.
#define KT 64
#define KSTR 136   // K LDS row stride (bf16): 2-way bank aliasing, 16B aligned
#define VSTR 72    // Vt/P LDS row stride

__global__ __launch_bounds__(256)
void attn_mfma_kernel(const unsigned short* __restrict__ Qb,
                      const unsigned short* __restrict__ Kb,
                      const unsigned short* __restrict__ Vtb,
                      const float* __restrict__ x,
                      const float* __restrict__ s2g,
                      float* __restrict__ out)
{
    const int q0 = blockIdx.x * 64;
    const int h  = blockIdx.y;
    const int b  = blockIdx.z;

    __shared__ unsigned short Ks[KT][KSTR];      // [kcol][feat]
    __shared__ unsigned short Vs[HF][VSTR];      // [feat][kcol]
    __shared__ unsigned short P1s[4][16][VSTR];  // per-wave [q][kcol]
    __shared__ unsigned short P2s[4][16][VSTR];

    const int tid  = threadIdx.x;
    const int w    = tid >> 6;
    const int lane = tid & 63;
    const int ln15 = lane & 15;
    const int quad = lane >> 4;

    const size_t bh = (size_t)b * H_DIM + h;
    const unsigned short* __restrict__ Qg = Qb + (bh * T_DIM + q0 + w * 16) * HF;
    const unsigned short* __restrict__ Kg = Kb + bh * T_DIM * HF;
    const unsigned short* __restrict__ Vg = Vtb + bh * HF * T_DIM;

    // Q A-fragments (held in registers for the whole kernel):
    // chunk c covers feats [32c, 32c+32); lane: m=ln15, k=quad*8+j
    short8 qa[4];
    #pragma unroll
    for (int c = 0; c < 4; ++c)
        qa[c] = *(const short8*)(Qg + (size_t)ln15 * HF + quad * 8 + 32 * c);

    floatx4 O1[8], O2[8];
    #pragma unroll
    for (int ft = 0; ft < 8; ++ft) {
        O1[ft] = (floatx4){0.f, 0.f, 0.f, 0.f};
        O2[ft] = (floatx4){0.f, 0.f, 0.f, 0.f};
    }
    float m1[4], l1[4], m2[4], l2[4];
    #pragma unroll
    for (int r = 0; r < 4; ++r) { m1[r] = -1e30f; l1[r] = 0.f; m2[r] = -1e30f; l2[r] = 0.f; }

    const float sc = 0.0625f;  // 1/sqrt(F/2)

    for (int k0 = 0; k0 < T_DIM; k0 += KT) {
        __syncthreads();
        // stage K tile [64 kcol][128 feat]: 64 rows x 16 chunks of 8 bf16
        #pragma unroll
        for (int it = 0; it < 4; ++it) {
            const int idx = tid + it * 256;
            const int r = idx >> 4, c = idx & 15;
            *(short8*)&Ks[r][c * 8] = *(const short8*)(Kg + (size_t)(k0 + r) * HF + c * 8);
        }
        // stage Vt tile [128 feat][64 kcol]: 128 rows x 8 chunks of 8 bf16
        #pragma unroll
        for (int it = 0; it < 4; ++it) {
            const int idx = tid + it * 256;
            const int r = idx >> 3, c = idx & 7;
            *(short8*)&Vs[r][c * 8] = *(const short8*)(Vg + (size_t)r * T_DIM + k0 + c * 8);
        }
        __syncthreads();

        // ---- scores: S1/S2 [16 q][64 kcol] via MFMA ----
        floatx4 S1[4], S2[4];
        #pragma unroll
        for (int nt = 0; nt < 4; ++nt) {
            const short8 kb0 = *(const short8*)&Ks[16*nt + ln15][quad*8];
            const short8 kb1 = *(const short8*)&Ks[16*nt + ln15][quad*8 + 32];
            const short8 kb2 = *(const short8*)&Ks[16*nt + ln15][quad*8 + 64];
            const short8 kb3 = *(const short8*)&Ks[16*nt + ln15][quad*8 + 96];
            floatx4 z = (floatx4){0.f, 0.f, 0.f, 0.f};
            floatx4 s = __builtin_amdgcn_mfma_f32_16x16x32_bf16(qa[0], kb0, z, 0, 0, 0);
            S1[nt]    = __builtin_amdgcn_mfma_f32_16x16x32_bf16(qa[1], kb1, s, 0, 0, 0);
            floatx4 u = __builtin_amdgcn_mfma_f32_16x16x32_bf16(qa[2], kb2, z, 0, 0, 0);
            S2[nt]    = __builtin_amdgcn_mfma_f32_16x16x32_bf16(qa[3], kb3, u, 0, 0, 0);
        }

        // ---- dual online softmax (row = quad*4 + r) ----
        float al1[4], al2[4];
        #pragma unroll
        for (int r = 0; r < 4; ++r) {
            const int qr = quad * 4 + r;
            {
                float a0 = S1[0][r]*sc, a1 = S1[1][r]*sc, a2 = S1[2][r]*sc, a3 = S1[3][r]*sc;
                float mx = fmaxf(fmaxf(a0, a1), fmaxf(a2, a3));
                mx = fmaxf(mx, __shfl_xor(mx, 1));
                mx = fmaxf(mx, __shfl_xor(mx, 2));
                mx = fmaxf(mx, __shfl_xor(mx, 4));
                mx = fmaxf(mx, __shfl_xor(mx, 8));
                const float mn = fmaxf(m1[r], mx);
                const float al = __expf(m1[r] - mn);
                m1[r] = mn; al1[r] = al;
                const float p0 = __expf(a0 - mn), p1 = __expf(a1 - mn);
                const float p2 = __expf(a2 - mn), p3 = __expf(a3 - mn);
                float sm = p0 + p1 + p2 + p3;
                sm += __shfl_xor(sm, 1); sm += __shfl_xor(sm, 2);
                sm += __shfl_xor(sm, 4); sm += __shfl_xor(sm, 8);
                l1[r] = l1[r] * al + sm;
                P1s[w][qr][ln15     ] = f2bf(p0);
                P1s[w][qr][ln15 + 16] = f2bf(p1);
                P1s[w][qr][ln15 + 32] = f2bf(p2);
                P1s[w][qr][ln15 + 48] = f2bf(p3);
            }
            {
                float a0 = S2[0][r]*sc, a1 = S2[1][r]*sc, a2 = S2[2][r]*sc, a3 = S2[3][r]*sc;
                float mx = fmaxf(fmaxf(a0, a1), fmaxf(a2, a3));
                mx = fmaxf(mx, __shfl_xor(mx, 1));
                mx = fmaxf(mx, __shfl_xor(mx, 2));
                mx = fmaxf(mx, __shfl_xor(mx, 4));
                mx = fmaxf(mx, __shfl_xor(mx, 8));
                const float mn = fmaxf(m2[r], mx);
                const float al = __expf(m2[r] - mn);
                m2[r] = mn; al2[r] = al;
                const float p0 = __expf(a0 - mn), p1 = __expf(a1 - mn);
                const float p2 = __expf(a2 - mn), p3 = __expf(a3 - mn);
                float sm = p0 + p1 + p2 + p3;
                sm += __shfl_xor(sm, 1); sm += __shfl_xor(sm, 2);
                sm += __shfl_xor(sm, 4); sm += __shfl_xor(sm, 8);
                l2[r] = l2[r] * al + sm;
                P2s[w][qr][ln15     ] = f2bf(p0);
                P2s[w][qr][ln15 + 16] = f2bf(p1);
                P2s[w][qr][ln15 + 32] = f2bf(p2);
                P2s[w][qr][ln15 + 48] = f2bf(p3);
            }
        }

        // rescale accumulators by alpha (per q-row = per reg)
        #pragma unroll
        for (int ft = 0; ft < 8; ++ft)
            #pragma unroll
            for (int r = 0; r < 4; ++r) { O1[ft][r] *= al1[r]; O2[ft][r] *= al2[r]; }

        // ---- PV: O += P @ V (A-frags from per-wave LDS; same-wave RAW,
        //      compiler inserts lgkmcnt wait — no barrier needed) ----
        const short8 pa10 = *(const short8*)&P1s[w][ln15][quad*8];
        const short8 pa11 = *(const short8*)&P1s[w][ln15][quad*8 + 32];
        const short8 pa20 = *(const short8*)&P2s[w][ln15][quad*8];
        const short8 pa21 = *(const short8*)&P2s[w][ln15][quad*8 + 32];
        #pragma unroll
        for (int ft = 0; ft < 8; ++ft) {
            const short8 vb0 = *(const short8*)&Vs[16*ft + ln15][quad*8];
            const short8 vb1 = *(const short8*)&Vs[16*ft + ln15][quad*8 + 32];
            O1[ft] = __builtin_amdgcn_mfma_f32_16x16x32_bf16(pa10, vb0, O1[ft], 0, 0, 0);
            O1[ft] = __builtin_amdgcn_mfma_f32_16x16x32_bf16(pa11, vb1, O1[ft], 0, 0, 0);
            O2[ft] = __builtin_amdgcn_mfma_f32_16x16x32_bf16(pa20, vb0, O2[ft], 0, 0, 0);
            O2[ft] = __builtin_amdgcn_mfma_f32_16x16x32_bf16(pa21, vb1, O2[ft], 0, 0, 0);
        }
    }

    // ---- epilogue: out = x + O1/l1 - s2*O2/l2, layout [B][F][T] ----
    const float s2h = s2g[h];
    float i1[4], i2[4];
    #pragma unroll
    for (int r = 0; r < 4; ++r) { i1[r] = 1.f / l1[r]; i2[r] = s2h / l2[r]; }

    const size_t obase = (size_t)b * F_DIM * T_DIM;
    const int f0 = h * HF;
    #pragma unroll
    for (int ft = 0; ft < 8; ++ft) {
        const int feat = 16 * ft + ln15;
        #pragma unroll
        for (int r = 0; r < 4; ++r) {
            const int t = q0 + w * 16 + quad * 4 + r;
            const size_t idx = obase + (size_t)(f0 + feat) * T_DIM + t;
            out[idx] = x[idx] + O1[ft][r] * i1[r] - O2[ft][r] * i2[r];
        }
    }
}

extern "C" void kernel_launch(void* const* d_in, const int* in_sizes, int n_in,
                              void* d_out, int out_size, void* d_ws, size_t ws_size,
                              hipStream_t stream)
{
    const float* x  = (const float*)d_in[0];
    const float* Wq = (const float*)d_in[1];
    const float* bq = (const float*)d_in[2];
    const float* Wk = (const float*)d_in[3];
    const float* bk = (const float*)d_in[4];
    const float* Wv = (const float*)d_in[5];
    const float* bv = (const float*)d_in[6];
    const float* s2 = (const float*)d_in[7];
    float* out = (float*)d_out;

    const size_t per = (size_t)B_DIM * H_DIM * T_DIM * HF;  // 4M elems (8 MB bf16)
    unsigned short* Qb  = (unsigned short*)d_ws;
    unsigned short* Kb  = Qb + per;
    unsigned short* Vtb = Kb + per;   // 24 MB total

    dim3 g1(T_DIM/64, F_DIM/64, B_DIM*3);
    hipLaunchKernelGGL(qkv_rope_kernel, g1, dim3(256), 0, stream,
                       x, Wq, bq, Wk, bk, Wv, bv, Qb, Kb, Vtb);

    dim3 g2(T_DIM/64, H_DIM, B_DIM);
    hipLaunchKernelGGL(attn_mfma_kernel, g2, dim3(256), 0, stream,
                       Qb, Kb, Vtb, x, s2, out);
}

// Round 3
// 306.788 us; speedup vs baseline: 4.3507x; 1.5734x over previous
//
#include <hip/hip_runtime.h>
#include <math.h>

#define B_DIM 4
#define F_DIM 512
#define T_DIM 2048
#define H_DIM 4
#define HF    128

typedef __attribute__((ext_vector_type(8))) short short8;
typedef __attribute__((ext_vector_type(4))) float floatx4;

__device__ __forceinline__ unsigned short f2bf(float f) {
    unsigned u = __float_as_uint(f);
    u += 0x7FFF + ((u >> 16) & 1);   // RNE
    return (unsigned short)(u >> 16);
}

__device__ __forceinline__ short8 pack8(const float* v) {
    short8 s;
    #pragma unroll
    for (int j = 0; j < 8; ++j) s[j] = (short)f2bf(v[j]);
    return s;
}

// ---------------- Kernel 0: prep ----------------
// z<4: transpose+convert x [B][F][T] fp32 -> xt [B][T][F] bf16 (64x64 LDS tiles)
// z==4: convert Wq/Wk/Wv fp32 -> bf16
__global__ __launch_bounds__(256)
void prep_kernel(const float* __restrict__ x,
                 const float* __restrict__ Wq, const float* __restrict__ Wk,
                 const float* __restrict__ Wv,
                 unsigned short* __restrict__ xt,
                 unsigned short* __restrict__ Wqb, unsigned short* __restrict__ Wkb,
                 unsigned short* __restrict__ Wvb)
{
    const int tid = threadIdx.x;
    if (blockIdx.z < B_DIM) {
        const int b  = blockIdx.z;
        const int t0 = blockIdx.x * 64;
        const int f0 = blockIdx.y * 64;
        __shared__ float Ls[64][67];   // odd-ish pad: scalar r/w both ~2-way
        const float* __restrict__ xb = x + (size_t)b * F_DIM * T_DIM;
        #pragma unroll
        for (int it = 0; it < 4; ++it) {
            const int fr = (tid >> 4) + 16 * it;
            const int tc = (tid & 15) << 2;
            const float4 v = *(const float4*)(xb + (size_t)(f0 + fr) * T_DIM + t0 + tc);
            Ls[fr][tc+0] = v.x; Ls[fr][tc+1] = v.y; Ls[fr][tc+2] = v.z; Ls[fr][tc+3] = v.w;
        }
        __syncthreads();
        const int f8 = tid & 7;
        const int tb = tid >> 3;   // 0..31
        #pragma unroll
        for (int it2 = 0; it2 < 2; ++it2) {
            const int t = tb + 32 * it2;
            float v[8];
            #pragma unroll
            for (int j = 0; j < 8; ++j) v[j] = Ls[8*f8 + j][t];
            *(short8*)(xt + ((size_t)b * T_DIM + t0 + t) * F_DIM + f0 + 8*f8) = pack8(v);
        }
    } else {
        const int blockId = blockIdx.y * 32 + blockIdx.x;  // 0..255
        const int g0 = blockId * 256 + tid;
        const int perW = F_DIM * F_DIM / 8;  // 32768 chunks of 8
        for (int chunk = g0; chunk < 3 * perW; chunk += 65536) {
            const int wsel = chunk / perW;
            const int rem  = chunk - wsel * perW;
            const float* __restrict__ Ws = (wsel == 0) ? Wq : (wsel == 1) ? Wk : Wv;
            unsigned short* __restrict__ Wd = (wsel == 0) ? Wqb : (wsel == 1) ? Wkb : Wvb;
            float v[8];
            *(float4*)&v[0] = *(const float4*)(Ws + (size_t)rem * 8);
            *(float4*)&v[4] = *(const float4*)(Ws + (size_t)rem * 8 + 4);
            *(short8*)(Wd + (size_t)rem * 8) = pack8(v);
        }
    }
}

// ---------------- Kernel 1: Q/K MFMA GEMM + bias + RoPE -------------------
// C[t][fo] = xt[t][:] . W[fo][:]; block = 128t x 64fo, BK=64, 4 waves.
// Output bf16 [B][T][512] (head h = cols h*128..h*128+127).
#define ASTR 72

__global__ __launch_bounds__(256)
void qk_gemm_rope_kernel(const unsigned short* __restrict__ xt,
                         const unsigned short* __restrict__ Wqb,
                         const unsigned short* __restrict__ Wkb,
                         const float* __restrict__ bq, const float* __restrict__ bk,
                         unsigned short* __restrict__ Qb, unsigned short* __restrict__ Kb)
{
    const int t0    = blockIdx.x * 128;
    const int fo0   = blockIdx.y * 64;
    const int b     = blockIdx.z >> 1;
    const int which = blockIdx.z & 1;
    const unsigned short* __restrict__ A  = xt + (size_t)b * T_DIM * F_DIM;
    const unsigned short* __restrict__ Bw = which ? Wkb : Wqb;
    const float* __restrict__ bias        = which ? bk : bq;
    unsigned short* __restrict__ Out = (which ? Kb : Qb) + (size_t)b * T_DIM * F_DIM;

    __shared__ unsigned short As[128][ASTR];
    __shared__ unsigned short Bs[64][ASTR];

    const int tid  = threadIdx.x;
    const int w    = tid >> 6;
    const int lane = tid & 63;
    const int ln15 = lane & 15;
    const int quad = lane >> 4;

    floatx4 acc[2][4];
    #pragma unroll
    for (int mi = 0; mi < 2; ++mi)
        #pragma unroll
        for (int nt = 0; nt < 4; ++nt) acc[mi][nt] = (floatx4){0.f,0.f,0.f,0.f};

    for (int f0 = 0; f0 < F_DIM; f0 += 64) {
        __syncthreads();
        #pragma unroll
        for (int it = 0; it < 4; ++it) {
            const int idx = tid + it * 256;
            const int r = idx >> 3, c = (idx & 7) * 8;
            *(short8*)&As[r][c] = *(const short8*)(A + (size_t)(t0 + r) * F_DIM + f0 + c);
        }
        #pragma unroll
        for (int it = 0; it < 2; ++it) {
            const int idx = tid + it * 256;
            const int r = idx >> 3, c = (idx & 7) * 8;
            *(short8*)&Bs[r][c] = *(const short8*)(Bw + (size_t)(fo0 + r) * F_DIM + f0 + c);
        }
        __syncthreads();
        #pragma unroll
        for (int ks = 0; ks < 2; ++ks) {
            short8 a[2], bb[4];
            a[0] = *(const short8*)&As[w*32      + ln15][ks*32 + quad*8];
            a[1] = *(const short8*)&As[w*32 + 16 + ln15][ks*32 + quad*8];
            #pragma unroll
            for (int nt = 0; nt < 4; ++nt)
                bb[nt] = *(const short8*)&Bs[16*nt + ln15][ks*32 + quad*8];
            #pragma unroll
            for (int mi = 0; mi < 2; ++mi)
                #pragma unroll
                for (int nt = 0; nt < 4; ++nt)
                    acc[mi][nt] = __builtin_amdgcn_mfma_f32_16x16x32_bf16(
                        a[mi], bb[nt], acc[mi][nt], 0, 0, 0);
        }
    }

    // Epilogue: bias + RoPE. n-span 64 covers one rope pair-group; cols nt and
    // nt+2 (32 apart) are pair partners on the same lane.
    float bn[4];
    #pragma unroll
    for (int nt = 0; nt < 4; ++nt) bn[nt] = bias[fo0 + 16*nt + ln15];

    #pragma unroll
    for (int mi = 0; mi < 2; ++mi) {
        #pragma unroll
        for (int r = 0; r < 4; ++r) {
            const int t = t0 + w*32 + 16*mi + quad*4 + r;
            unsigned short* rowp = Out + (size_t)t * F_DIM + fo0;
            #pragma unroll
            for (int pr = 0; pr < 2; ++pr) {
                const int wi = 16*pr + ln15;                     // 0..31
                const float re = acc[mi][pr  ][r] + bn[pr];
                const float im = acc[mi][pr+2][r] + bn[pr+2];
                const float u = ldexpf((float)t, -wi) * 0.0625f; // t*2^-wi/16
                float sn, cs;
                sincosf(u, &sn, &cs);
                rowp[wi]      = f2bf(re * sn - im * cs);
                rowp[wi + 32] = f2bf(re * cs + im * sn);
            }
        }
    }
}

// ---------------- Kernel 2: V^T MFMA GEMM (A=Wv, B=xt -> D[fo][t]) --------
__global__ __launch_bounds__(256)
void vt_gemm_kernel(const unsigned short* __restrict__ xt,
                    const unsigned short* __restrict__ Wvb,
                    const float* __restrict__ bv,
                    unsigned short* __restrict__ Vtb)
{
    const int fo0 = blockIdx.x * 128;
    const int t0  = blockIdx.y * 64;
    const int b   = blockIdx.z;
    const unsigned short* __restrict__ Bx = xt + (size_t)b * T_DIM * F_DIM;

    __shared__ unsigned short As[128][ASTR];  // Wv rows (fo)
    __shared__ unsigned short Bs[64][ASTR];   // xt rows (t)

    const int tid  = threadIdx.x;
    const int w    = tid >> 6;
    const int lane = tid & 63;
    const int ln15 = lane & 15;
    const int quad = lane >> 4;

    floatx4 acc[2][4];
    #pragma unroll
    for (int mi = 0; mi < 2; ++mi)
        #pragma unroll
        for (int nt = 0; nt < 4; ++nt) acc[mi][nt] = (floatx4){0.f,0.f,0.f,0.f};

    for (int f0 = 0; f0 < F_DIM; f0 += 64) {
        __syncthreads();
        #pragma unroll
        for (int it = 0; it < 4; ++it) {
            const int idx = tid + it * 256;
            const int r = idx >> 3, c = (idx & 7) * 8;
            *(short8*)&As[r][c] = *(const short8*)(Wvb + (size_t)(fo0 + r) * F_DIM + f0 + c);
        }
        #pragma unroll
        for (int it = 0; it < 2; ++it) {
            const int idx = tid + it * 256;
            const int r = idx >> 3, c = (idx & 7) * 8;
            *(short8*)&Bs[r][c] = *(const short8*)(Bx + (size_t)(t0 + r) * F_DIM + f0 + c);
        }
        __syncthreads();
        #pragma unroll
        for (int ks = 0; ks < 2; ++ks) {
            short8 a[2], bb[4];
            a[0] = *(const short8*)&As[w*32      + ln15][ks*32 + quad*8];
            a[1] = *(const short8*)&As[w*32 + 16 + ln15][ks*32 + quad*8];
            #pragma unroll
            for (int nt = 0; nt < 4; ++nt)
                bb[nt] = *(const short8*)&Bs[16*nt + ln15][ks*32 + quad*8];
            #pragma unroll
            for (int mi = 0; mi < 2; ++mi)
                #pragma unroll
                for (int nt = 0; nt < 4; ++nt)
                    acc[mi][nt] = __builtin_amdgcn_mfma_f32_16x16x32_bf16(
                        a[mi], bb[nt], acc[mi][nt], 0, 0, 0);
        }
    }

    // Epilogue: bias (row fo) + store Vt[b][fo][t] (cols t -> along-t stores)
    #pragma unroll
    for (int mi = 0; mi < 2; ++mi) {
        #pragma unroll
        for (int r = 0; r < 4; ++r) {
            const int fo = fo0 + w*32 + 16*mi + quad*4 + r;
            const float bvv = bv[fo];
            unsigned short* rowp = Vtb + ((size_t)b * F_DIM + fo) * T_DIM + t0;
            #pragma unroll
            for (int nt = 0; nt < 4; ++nt)
                rowp[16*nt + ln15] = f2bf(acc[mi][nt][r] + bvv);
        }
    }
}

// ---------------- Kernel 3: MFMA flash attention (dual softmax) ------------
// Q,K: bf16 [B][T][512] (head = 128-col slice). Vt: bf16 [B][512][T].
#define KT 64
#define KSTR 136
#define VSTR 72

__global__ __launch_bounds__(256)
void attn_mfma_kernel(const unsigned short* __restrict__ Qb,
                      const unsigned short* __restrict__ Kb,
                      const unsigned short* __restrict__ Vtb,
                      const float* __restrict__ x,
                      const float* __restrict__ s2g,
                      float* __restrict__ out)
{
    const int q0 = blockIdx.x * 64;
    const int h  = blockIdx.y;
    const int b  = blockIdx.z;

    __shared__ unsigned short Ks[KT][KSTR];      // [kcol][feat]
    __shared__ unsigned short Vs[HF][VSTR];      // [feat][kcol]
    __shared__ unsigned short P1s[4][16][VSTR];  // per-wave [q][kcol]
    __shared__ unsigned short P2s[4][16][VSTR];

    const int tid  = threadIdx.x;
    const int w    = tid >> 6;
    const int lane = tid & 63;
    const int ln15 = lane & 15;
    const int quad = lane >> 4;

    const unsigned short* __restrict__ Qg =
        Qb + ((size_t)b * T_DIM + q0 + w * 16) * F_DIM + h * HF;
    const unsigned short* __restrict__ Kg =
        Kb + (size_t)b * T_DIM * F_DIM + h * HF;
    const unsigned short* __restrict__ Vg =
        Vtb + ((size_t)b * F_DIM + h * HF) * T_DIM;

    short8 qa[4];
    #pragma unroll
    for (int c = 0; c < 4; ++c)
        qa[c] = *(const short8*)(Qg + (size_t)ln15 * F_DIM + quad * 8 + 32 * c);

    floatx4 O1[8], O2[8];
    #pragma unroll
    for (int ft = 0; ft < 8; ++ft) {
        O1[ft] = (floatx4){0.f, 0.f, 0.f, 0.f};
        O2[ft] = (floatx4){0.f, 0.f, 0.f, 0.f};
    }
    float m1[4], l1[4], m2[4], l2[4];
    #pragma unroll
    for (int r = 0; r < 4; ++r) { m1[r] = -1e30f; l1[r] = 0.f; m2[r] = -1e30f; l2[r] = 0.f; }

    const float sc = 0.0625f;  // 1/sqrt(F/2)

    for (int k0 = 0; k0 < T_DIM; k0 += KT) {
        __syncthreads();
        #pragma unroll
        for (int it = 0; it < 4; ++it) {
            const int idx = tid + it * 256;
            const int r = idx >> 4, c = idx & 15;
            *(short8*)&Ks[r][c * 8] =
                *(const short8*)(Kg + (size_t)(k0 + r) * F_DIM + c * 8);
        }
        #pragma unroll
        for (int it = 0; it < 4; ++it) {
            const int idx = tid + it * 256;
            const int r = idx >> 3, c = idx & 7;
            *(short8*)&Vs[r][c * 8] =
                *(const short8*)(Vg + (size_t)r * T_DIM + k0 + c * 8);
        }
        __syncthreads();

        floatx4 S1[4], S2[4];
        #pragma unroll
        for (int nt = 0; nt < 4; ++nt) {
            const short8 kb0 = *(const short8*)&Ks[16*nt + ln15][quad*8];
            const short8 kb1 = *(const short8*)&Ks[16*nt + ln15][quad*8 + 32];
            const short8 kb2 = *(const short8*)&Ks[16*nt + ln15][quad*8 + 64];
            const short8 kb3 = *(const short8*)&Ks[16*nt + ln15][quad*8 + 96];
            floatx4 z = (floatx4){0.f, 0.f, 0.f, 0.f};
            floatx4 s = __builtin_amdgcn_mfma_f32_16x16x32_bf16(qa[0], kb0, z, 0, 0, 0);
            S1[nt]    = __builtin_amdgcn_mfma_f32_16x16x32_bf16(qa[1], kb1, s, 0, 0, 0);
            floatx4 u = __builtin_amdgcn_mfma_f32_16x16x32_bf16(qa[2], kb2, z, 0, 0, 0);
            S2[nt]    = __builtin_amdgcn_mfma_f32_16x16x32_bf16(qa[3], kb3, u, 0, 0, 0);
        }

        float al1[4], al2[4];
        #pragma unroll
        for (int r = 0; r < 4; ++r) {
            const int qr = quad * 4 + r;
            {
                float a0 = S1[0][r]*sc, a1 = S1[1][r]*sc, a2 = S1[2][r]*sc, a3 = S1[3][r]*sc;
                float mx = fmaxf(fmaxf(a0, a1), fmaxf(a2, a3));
                mx = fmaxf(mx, __shfl_xor(mx, 1));
                mx = fmaxf(mx, __shfl_xor(mx, 2));
                mx = fmaxf(mx, __shfl_xor(mx, 4));
                mx = fmaxf(mx, __shfl_xor(mx, 8));
                const float mn = fmaxf(m1[r], mx);
                const float al = __expf(m1[r] - mn);
                m1[r] = mn; al1[r] = al;
                const float p0 = __expf(a0 - mn), p1 = __expf(a1 - mn);
                const float p2 = __expf(a2 - mn), p3 = __expf(a3 - mn);
                float sm = p0 + p1 + p2 + p3;
                sm += __shfl_xor(sm, 1); sm += __shfl_xor(sm, 2);
                sm += __shfl_xor(sm, 4); sm += __shfl_xor(sm, 8);
                l1[r] = l1[r] * al + sm;
                P1s[w][qr][ln15     ] = f2bf(p0);
                P1s[w][qr][ln15 + 16] = f2bf(p1);
                P1s[w][qr][ln15 + 32] = f2bf(p2);
                P1s[w][qr][ln15 + 48] = f2bf(p3);
            }
            {
                float a0 = S2[0][r]*sc, a1 = S2[1][r]*sc, a2 = S2[2][r]*sc, a3 = S2[3][r]*sc;
                float mx = fmaxf(fmaxf(a0, a1), fmaxf(a2, a3));
                mx = fmaxf(mx, __shfl_xor(mx, 1));
                mx = fmaxf(mx, __shfl_xor(mx, 2));
                mx = fmaxf(mx, __shfl_xor(mx, 4));
                mx = fmaxf(mx, __shfl_xor(mx, 8));
                const float mn = fmaxf(m2[r], mx);
                const float al = __expf(m2[r] - mn);
                m2[r] = mn; al2[r] = al;
                const float p0 = __expf(a0 - mn), p1 = __expf(a1 - mn);
                const float p2 = __expf(a2 - mn), p3 = __expf(a3 - mn);
                float sm = p0 + p1 + p2 + p3;
                sm += __shfl_xor(sm, 1); sm += __shfl_xor(sm, 2);
                sm += __shfl_xor(sm, 4); sm += __shfl_xor(sm, 8);
                l2[r] = l2[r] * al + sm;
                P2s[w][qr][ln15     ] = f2bf(p0);
                P2s[w][qr][ln15 + 16] = f2bf(p1);
                P2s[w][qr][ln15 + 32] = f2bf(p2);
                P2s[w][qr][ln15 + 48] = f2bf(p3);
            }
        }

        #pragma unroll
        for (int ft = 0; ft < 8; ++ft)
            #pragma unroll
            for (int r = 0; r < 4; ++r) { O1[ft][r] *= al1[r]; O2[ft][r] *= al2[r]; }

        const short8 pa10 = *(const short8*)&P1s[w][ln15][quad*8];
        const short8 pa11 = *(const short8*)&P1s[w][ln15][quad*8 + 32];
        const short8 pa20 = *(const short8*)&P2s[w][ln15][quad*8];
        const short8 pa21 = *(const short8*)&P2s[w][ln15][quad*8 + 32];
        #pragma unroll
        for (int ft = 0; ft < 8; ++ft) {
            const short8 vb0 = *(const short8*)&Vs[16*ft + ln15][quad*8];
            const short8 vb1 = *(const short8*)&Vs[16*ft + ln15][quad*8 + 32];
            O1[ft] = __builtin_amdgcn_mfma_f32_16x16x32_bf16(pa10, vb0, O1[ft], 0, 0, 0);
            O1[ft] = __builtin_amdgcn_mfma_f32_16x16x32_bf16(pa11, vb1, O1[ft], 0, 0, 0);
            O2[ft] = __builtin_amdgcn_mfma_f32_16x16x32_bf16(pa20, vb0, O2[ft], 0, 0, 0);
            O2[ft] = __builtin_amdgcn_mfma_f32_16x16x32_bf16(pa21, vb1, O2[ft], 0, 0, 0);
        }
    }

    const float s2h = s2g[h];
    float i1[4], i2[4];
    #pragma unroll
    for (int r = 0; r < 4; ++r) { i1[r] = 1.f / l1[r]; i2[r] = s2h / l2[r]; }

    const size_t obase = (size_t)b * F_DIM * T_DIM;
    const int f0 = h * HF;
    #pragma unroll
    for (int ft = 0; ft < 8; ++ft) {
        const int feat = 16 * ft + ln15;
        #pragma unroll
        for (int r = 0; r < 4; ++r) {
            const int t = q0 + w * 16 + quad * 4 + r;
            const size_t idx = obase + (size_t)(f0 + feat) * T_DIM + t;
            out[idx] = x[idx] + O1[ft][r] * i1[r] - O2[ft][r] * i2[r];
        }
    }
}

extern "C" void kernel_launch(void* const* d_in, const int* in_sizes, int n_in,
                              void* d_out, int out_size, void* d_ws, size_t ws_size,
                              hipStream_t stream)
{
    const float* x  = (const float*)d_in[0];
    const float* Wq = (const float*)d_in[1];
    const float* bq = (const float*)d_in[2];
    const float* Wk = (const float*)d_in[3];
    const float* bk = (const float*)d_in[4];
    const float* Wv = (const float*)d_in[5];
    const float* bv = (const float*)d_in[6];
    const float* s2 = (const float*)d_in[7];
    float* out = (float*)d_out;

    const size_t per = (size_t)B_DIM * T_DIM * F_DIM;  // 4M elems
    const size_t wsz = (size_t)F_DIM * F_DIM;          // 256K elems
    unsigned short* xt  = (unsigned short*)d_ws;
    unsigned short* Wqb = xt + per;
    unsigned short* Wkb = Wqb + wsz;
    unsigned short* Wvb = Wkb + wsz;
    unsigned short* Qb  = Wvb + wsz;
    unsigned short* Kb  = Qb + per;
    unsigned short* Vtb = Kb + per;   // total ~33.5 MB

    hipLaunchKernelGGL(prep_kernel, dim3(32, 8, 5), dim3(256), 0, stream,
                       x, Wq, Wk, Wv, xt, Wqb, Wkb, Wvb);

    hipLaunchKernelGGL(qk_gemm_rope_kernel, dim3(16, 8, 8), dim3(256), 0, stream,
                       xt, Wqb, Wkb, bq, bk, Qb, Kb);

    hipLaunchKernelGGL(vt_gemm_kernel, dim3(4, 32, 4), dim3(256), 0, stream,
                       xt, Wvb, bv, Vtb);

    hipLaunchKernelGGL(attn_mfma_kernel, dim3(32, 4, 4), dim3(256), 0, stream,
                       Qb, Kb, Vtb, x, s2, out);
}

// Round 4
// 192.169 us; speedup vs baseline: 6.9457x; 1.5965x over previous
//
#include <hip/hip_runtime.h>
#include <math.h>

#define B_DIM 4
#define F_DIM 512
#define T_DIM 2048
#define H_DIM 4
#define HF    128

typedef __attribute__((ext_vector_type(8))) short short8;
typedef __attribute__((ext_vector_type(4))) float floatx4;

__device__ __forceinline__ unsigned short f2bf(float f) {
    unsigned u = __float_as_uint(f);
    u += 0x7FFF + ((u >> 16) & 1);   // RNE
    return (unsigned short)(u >> 16);
}

__device__ __forceinline__ short8 pack8(const float* v) {
    short8 s;
    #pragma unroll
    for (int j = 0; j < 8; ++j) s[j] = (short)f2bf(v[j]);
    return s;
}

// ---------------- Kernel 0: prep ----------------
// z<4: transpose+convert x [B][F][T] fp32 -> xt [B][T][F] bf16 (64x64 LDS tiles)
// z==4: convert Wq/Wk/Wv fp32 -> bf16
__global__ __launch_bounds__(256)
void prep_kernel(const float* __restrict__ x,
                 const float* __restrict__ Wq, const float* __restrict__ Wk,
                 const float* __restrict__ Wv,
                 unsigned short* __restrict__ xt,
                 unsigned short* __restrict__ Wqb, unsigned short* __restrict__ Wkb,
                 unsigned short* __restrict__ Wvb)
{
    const int tid = threadIdx.x;
    if (blockIdx.z < B_DIM) {
        const int b  = blockIdx.z;
        const int t0 = blockIdx.x * 64;
        const int f0 = blockIdx.y * 64;
        __shared__ float Ls[64][67];
        const float* __restrict__ xb = x + (size_t)b * F_DIM * T_DIM;
        #pragma unroll
        for (int it = 0; it < 4; ++it) {
            const int fr = (tid >> 4) + 16 * it;
            const int tc = (tid & 15) << 2;
            const float4 v = *(const float4*)(xb + (size_t)(f0 + fr) * T_DIM + t0 + tc);
            Ls[fr][tc+0] = v.x; Ls[fr][tc+1] = v.y; Ls[fr][tc+2] = v.z; Ls[fr][tc+3] = v.w;
        }
        __syncthreads();
        const int f8 = tid & 7;
        const int tb = tid >> 3;   // 0..31
        #pragma unroll
        for (int it2 = 0; it2 < 2; ++it2) {
            const int t = tb + 32 * it2;
            float v[8];
            #pragma unroll
            for (int j = 0; j < 8; ++j) v[j] = Ls[8*f8 + j][t];
            *(short8*)(xt + ((size_t)b * T_DIM + t0 + t) * F_DIM + f0 + 8*f8) = pack8(v);
        }
    } else {
        const int blockId = blockIdx.y * 32 + blockIdx.x;  // 0..255
        const int g0 = blockId * 256 + tid;
        const int perW = F_DIM * F_DIM / 8;  // 32768 chunks of 8
        for (int chunk = g0; chunk < 3 * perW; chunk += 65536) {
            const int wsel = chunk / perW;
            const int rem  = chunk - wsel * perW;
            const float* __restrict__ Ws = (wsel == 0) ? Wq : (wsel == 1) ? Wk : Wv;
            unsigned short* __restrict__ Wd = (wsel == 0) ? Wqb : (wsel == 1) ? Wkb : Wvb;
            float v[8];
            *(float4*)&v[0] = *(const float4*)(Ws + (size_t)rem * 8);
            *(float4*)&v[4] = *(const float4*)(Ws + (size_t)rem * 8 + 4);
            *(short8*)(Wd + (size_t)rem * 8) = pack8(v);
        }
    }
}

// ---------------- Kernel 1: Q/K MFMA GEMM + bias + RoPE -------------------
// C[t][fo] = xt[t][:] . W[fo][:]; block = 128t x 64fo, BK=64, 4 waves.
// Output bf16 [B][T][512]. Q additionally scaled by 1/16 (softmax scale folded).
#define ASTR 72

__global__ __launch_bounds__(256)
void qk_gemm_rope_kernel(const unsigned short* __restrict__ xt,
                         const unsigned short* __restrict__ Wqb,
                         const unsigned short* __restrict__ Wkb,
                         const float* __restrict__ bq, const float* __restrict__ bk,
                         unsigned short* __restrict__ Qb, unsigned short* __restrict__ Kb)
{
    const int t0    = blockIdx.x * 128;
    const int fo0   = blockIdx.y * 64;
    const int b     = blockIdx.z >> 1;
    const int which = blockIdx.z & 1;
    const unsigned short* __restrict__ A  = xt + (size_t)b * T_DIM * F_DIM;
    const unsigned short* __restrict__ Bw = which ? Wkb : Wqb;
    const float* __restrict__ bias        = which ? bk : bq;
    unsigned short* __restrict__ Out = (which ? Kb : Qb) + (size_t)b * T_DIM * F_DIM;
    const float oscale = which ? 1.0f : 0.0625f;   // fold 1/sqrt(F/2) into Q

    __shared__ unsigned short As[128][ASTR];
    __shared__ unsigned short Bs[64][ASTR];

    const int tid  = threadIdx.x;
    const int w    = tid >> 6;
    const int lane = tid & 63;
    const int ln15 = lane & 15;
    const int quad = lane >> 4;

    floatx4 acc[2][4];
    #pragma unroll
    for (int mi = 0; mi < 2; ++mi)
        #pragma unroll
        for (int nt = 0; nt < 4; ++nt) acc[mi][nt] = (floatx4){0.f,0.f,0.f,0.f};

    for (int f0 = 0; f0 < F_DIM; f0 += 64) {
        __syncthreads();
        #pragma unroll
        for (int it = 0; it < 4; ++it) {
            const int idx = tid + it * 256;
            const int r = idx >> 3, c = (idx & 7) * 8;
            *(short8*)&As[r][c] = *(const short8*)(A + (size_t)(t0 + r) * F_DIM + f0 + c);
        }
        #pragma unroll
        for (int it = 0; it < 2; ++it) {
            const int idx = tid + it * 256;
            const int r = idx >> 3, c = (idx & 7) * 8;
            *(short8*)&Bs[r][c] = *(const short8*)(Bw + (size_t)(fo0 + r) * F_DIM + f0 + c);
        }
        __syncthreads();
        #pragma unroll
        for (int ks = 0; ks < 2; ++ks) {
            short8 a[2], bb[4];
            a[0] = *(const short8*)&As[w*32      + ln15][ks*32 + quad*8];
            a[1] = *(const short8*)&As[w*32 + 16 + ln15][ks*32 + quad*8];
            #pragma unroll
            for (int nt = 0; nt < 4; ++nt)
                bb[nt] = *(const short8*)&Bs[16*nt + ln15][ks*32 + quad*8];
            #pragma unroll
            for (int mi = 0; mi < 2; ++mi)
                #pragma unroll
                for (int nt = 0; nt < 4; ++nt)
                    acc[mi][nt] = __builtin_amdgcn_mfma_f32_16x16x32_bf16(
                        a[mi], bb[nt], acc[mi][nt], 0, 0, 0);
        }
    }

    float bn[4];
    #pragma unroll
    for (int nt = 0; nt < 4; ++nt) bn[nt] = bias[fo0 + 16*nt + ln15];

    #pragma unroll
    for (int mi = 0; mi < 2; ++mi) {
        #pragma unroll
        for (int r = 0; r < 4; ++r) {
            const int t = t0 + w*32 + 16*mi + quad*4 + r;
            unsigned short* rowp = Out + (size_t)t * F_DIM + fo0;
            #pragma unroll
            for (int pr = 0; pr < 2; ++pr) {
                const int wi = 16*pr + ln15;                     // 0..31
                const float re = acc[mi][pr  ][r] + bn[pr];
                const float im = acc[mi][pr+2][r] + bn[pr+2];
                const float u = ldexpf((float)t, -wi) * 0.0625f; // t*2^-wi/16
                float sn, cs;
                sincosf(u, &sn, &cs);
                rowp[wi]      = f2bf((re * sn - im * cs) * oscale);
                rowp[wi + 32] = f2bf((re * cs + im * sn) * oscale);
            }
        }
    }
}

// ---------------- Kernel 2: V^T MFMA GEMM (A=Wv, B=xt -> D[fo][t]) --------
__global__ __launch_bounds__(256)
void vt_gemm_kernel(const unsigned short* __restrict__ xt,
                    const unsigned short* __restrict__ Wvb,
                    const float* __restrict__ bv,
                    unsigned short* __restrict__ Vtb)
{
    const int fo0 = blockIdx.x * 128;
    const int t0  = blockIdx.y * 64;
    const int b   = blockIdx.z;
    const unsigned short* __restrict__ Bx = xt + (size_t)b * T_DIM * F_DIM;

    __shared__ unsigned short As[128][ASTR];
    __shared__ unsigned short Bs[64][ASTR];

    const int tid  = threadIdx.x;
    const int w    = tid >> 6;
    const int lane = tid & 63;
    const int ln15 = lane & 15;
    const int quad = lane >> 4;

    floatx4 acc[2][4];
    #pragma unroll
    for (int mi = 0; mi < 2; ++mi)
        #pragma unroll
        for (int nt = 0; nt < 4; ++nt) acc[mi][nt] = (floatx4){0.f,0.f,0.f,0.f};

    for (int f0 = 0; f0 < F_DIM; f0 += 64) {
        __syncthreads();
        #pragma unroll
        for (int it = 0; it < 4; ++it) {
            const int idx = tid + it * 256;
            const int r = idx >> 3, c = (idx & 7) * 8;
            *(short8*)&As[r][c] = *(const short8*)(Wvb + (size_t)(fo0 + r) * F_DIM + f0 + c);
        }
        #pragma unroll
        for (int it = 0; it < 2; ++it) {
            const int idx = tid + it * 256;
            const int r = idx >> 3, c = (idx & 7) * 8;
            *(short8*)&Bs[r][c] = *(const short8*)(Bx + (size_t)(t0 + r) * F_DIM + f0 + c);
        }
        __syncthreads();
        #pragma unroll
        for (int ks = 0; ks < 2; ++ks) {
            short8 a[2], bb[4];
            a[0] = *(const short8*)&As[w*32      + ln15][ks*32 + quad*8];
            a[1] = *(const short8*)&As[w*32 + 16 + ln15][ks*32 + quad*8];
            #pragma unroll
            for (int nt = 0; nt < 4; ++nt)
                bb[nt] = *(const short8*)&Bs[16*nt + ln15][ks*32 + quad*8];
            #pragma unroll
            for (int mi = 0; mi < 2; ++mi)
                #pragma unroll
                for (int nt = 0; nt < 4; ++nt)
                    acc[mi][nt] = __builtin_amdgcn_mfma_f32_16x16x32_bf16(
                        a[mi], bb[nt], acc[mi][nt], 0, 0, 0);
        }
    }

    #pragma unroll
    for (int mi = 0; mi < 2; ++mi) {
        #pragma unroll
        for (int r = 0; r < 4; ++r) {
            const int fo = fo0 + w*32 + 16*mi + quad*4 + r;
            const float bvv = bv[fo];
            unsigned short* rowp = Vtb + ((size_t)b * F_DIM + fo) * T_DIM + t0;
            #pragma unroll
            for (int nt = 0; nt < 4; ++nt)
                rowp[16*nt + ln15] = f2bf(acc[mi][nt][r] + bvv);
        }
    }
}

// ---------------- Kernel 3: S^T MFMA flash attention (dual softmax) --------
// Computes S^T = K.Q^T so each lane owns ONE q-row (q=lane&15); P^T C-regs feed
// the PV MFMA directly as B-operand (no LDS round-trip). K rows stored
// bit-permuted (row' = p<<5|ct<<4|q2<<2|rb) so C-tile pair (2p,2p+1) packs into
// one K=32 B-frag whose slot k == actual kcol. KSTR=136 (17 granules, odd) and
// VSTR=72 (9 granules) put every b128 access at the bank floor.
#define KT 64
#define KSTR 136
#define VSTR 72

__global__ __launch_bounds__(256, 2)
void attn_mfma_kernel(const unsigned short* __restrict__ Qb,
                      const unsigned short* __restrict__ Kb,
                      const unsigned short* __restrict__ Vtb,
                      const float* __restrict__ x,
                      const float* __restrict__ s2g,
                      float* __restrict__ out)
{
    const int q0 = blockIdx.x * 64;
    const int h  = blockIdx.y;
    const int b  = blockIdx.z;

    __shared__ unsigned short Ks[KT][KSTR];   // row-permuted [kcol'][feat]
    __shared__ unsigned short Vs[HF][VSTR];   // [feat][kcol]

    const int tid  = threadIdx.x;
    const int w    = tid >> 6;
    const int lane = tid & 63;
    const int ln15 = lane & 15;
    const int quad = lane >> 4;

    const unsigned short* __restrict__ Qg =
        Qb + ((size_t)b * T_DIM + q0 + w * 16) * F_DIM + h * HF;
    const unsigned short* __restrict__ Kg =
        Kb + (size_t)b * T_DIM * F_DIM + h * HF;
    const unsigned short* __restrict__ Vg =
        Vtb + ((size_t)b * F_DIM + h * HF) * T_DIM;

    // Q B-fragments, resident for the whole kernel: B[k=feat][n=q], n=ln15.
    short8 qa[4];
    #pragma unroll
    for (int c = 0; c < 4; ++c)
        qa[c] = *(const short8*)(Qg + (size_t)ln15 * F_DIM + quad * 8 + 32 * c);

    // O^T accumulators: lane holds O^T[feat=16ft+4quad+r][q=ln15]
    floatx4 O1t[8], O2t[8];
    #pragma unroll
    for (int ft = 0; ft < 8; ++ft) {
        O1t[ft] = (floatx4){0.f, 0.f, 0.f, 0.f};
        O2t[ft] = (floatx4){0.f, 0.f, 0.f, 0.f};
    }
    float m1 = -1e30f, l1 = 0.f, m2 = -1e30f, l2 = 0.f;

    // staging prefetch registers
    short8 kpre[4], vpre[4];
    {
        #pragma unroll
        for (int it = 0; it < 4; ++it) {
            const int idx = tid + it * 256;
            const int r = idx >> 4, c = idx & 15;
            kpre[it] = *(const short8*)(Kg + (size_t)r * F_DIM + c * 8);
        }
        #pragma unroll
        for (int it = 0; it < 4; ++it) {
            const int idx = tid + it * 256;
            const int r = idx >> 3, c = idx & 7;
            vpre[it] = *(const short8*)(Vg + (size_t)r * T_DIM + c * 8);
        }
    }

    for (int k0 = 0; k0 < T_DIM; k0 += KT) {
        __syncthreads();   // readers of previous tile done
        #pragma unroll
        for (int it = 0; it < 4; ++it) {
            const int idx = tid + it * 256;
            const int r = idx >> 4, c = idx & 15;
            // bit-permuted row: r = 32p+8q2+4ct+rb -> 32p+16ct+4q2+rb
            const int rp = (r & 32) | ((r & 4) << 2) | ((r & 24) >> 1) | (r & 3);
            *(short8*)&Ks[rp][c * 8] = kpre[it];
        }
        #pragma unroll
        for (int it = 0; it < 4; ++it) {
            const int idx = tid + it * 256;
            const int r = idx >> 3, c = idx & 7;
            *(short8*)&Vs[r][c * 8] = vpre[it];
        }
        __syncthreads();   // tile visible

        // prefetch next tile (in flight across the whole compute phase)
        if (k0 + KT < T_DIM) {
            #pragma unroll
            for (int it = 0; it < 4; ++it) {
                const int idx = tid + it * 256;
                const int r = idx >> 4, c = idx & 15;
                kpre[it] = *(const short8*)(Kg + (size_t)(k0 + KT + r) * F_DIM + c * 8);
            }
            #pragma unroll
            for (int it = 0; it < 4; ++it) {
                const int idx = tid + it * 256;
                const int r = idx >> 3, c = idx & 7;
                vpre[it] = *(const short8*)(Vg + (size_t)r * T_DIM + k0 + KT + c * 8);
            }
        }

        // ---- scores S^T: tile t rows are Ks rows 16t+ln15 (contiguous) ----
        floatx4 S1t[4], S2t[4];
        #pragma unroll
        for (int t = 0; t < 4; ++t) {
            const unsigned short* krow = &Ks[16*t + ln15][0];
            const short8 k0f = *(const short8*)(krow + quad*8);
            const short8 k1f = *(const short8*)(krow + quad*8 + 32);
            const short8 k2f = *(const short8*)(krow + quad*8 + 64);
            const short8 k3f = *(const short8*)(krow + quad*8 + 96);
            floatx4 z = (floatx4){0.f, 0.f, 0.f, 0.f};
            floatx4 s = __builtin_amdgcn_mfma_f32_16x16x32_bf16(k0f, qa[0], z, 0, 0, 0);
            S1t[t]    = __builtin_amdgcn_mfma_f32_16x16x32_bf16(k1f, qa[1], s, 0, 0, 0);
            floatx4 u = __builtin_amdgcn_mfma_f32_16x16x32_bf16(k2f, qa[2], z, 0, 0, 0);
            S2t[t]    = __builtin_amdgcn_mfma_f32_16x16x32_bf16(k3f, qa[3], u, 0, 0, 0);
        }

        // ---- dual online softmax: all 16 values per lane share q=ln15 ----
        float e1[16], e2[16];
        float al1, al2;
        {
            float mx = S1t[0][0];
            #pragma unroll
            for (int t = 0; t < 4; ++t)
                #pragma unroll
                for (int r = 0; r < 4; ++r) mx = fmaxf(mx, S1t[t][r]);
            mx = fmaxf(mx, __shfl_xor(mx, 16));
            mx = fmaxf(mx, __shfl_xor(mx, 32));
            const float mn = fmaxf(m1, mx);
            al1 = __expf(m1 - mn); m1 = mn;
            float sm = 0.f;
            #pragma unroll
            for (int t = 0; t < 4; ++t)
                #pragma unroll
                for (int r = 0; r < 4; ++r) {
                    const float e = __expf(S1t[t][r] - mn);
                    e1[4*t + r] = e; sm += e;
                }
            sm += __shfl_xor(sm, 16);
            sm += __shfl_xor(sm, 32);
            l1 = l1 * al1 + sm;
        }
        {
            float mx = S2t[0][0];
            #pragma unroll
            for (int t = 0; t < 4; ++t)
                #pragma unroll
                for (int r = 0; r < 4; ++r) mx = fmaxf(mx, S2t[t][r]);
            mx = fmaxf(mx, __shfl_xor(mx, 16));
            mx = fmaxf(mx, __shfl_xor(mx, 32));
            const float mn = fmaxf(m2, mx);
            al2 = __expf(m2 - mn); m2 = mn;
            float sm = 0.f;
            #pragma unroll
            for (int t = 0; t < 4; ++t)
                #pragma unroll
                for (int r = 0; r < 4; ++r) {
                    const float e = __expf(S2t[t][r] - mn);
                    e2[4*t + r] = e; sm += e;
                }
            sm += __shfl_xor(sm, 16);
            sm += __shfl_xor(sm, 32);
            l2 = l2 * al2 + sm;
        }

        // P^T B-frags: pair p = tiles (2p, 2p+1); slot k == kcol 32p+8quad+k
        short8 p1f[2], p2f[2];
        p1f[0] = pack8(&e1[0]);  p1f[1] = pack8(&e1[8]);
        p2f[0] = pack8(&e2[0]);  p2f[1] = pack8(&e2[8]);

        // rescale accumulators (alpha uniform per lane)
        #pragma unroll
        for (int ft = 0; ft < 8; ++ft) {
            #pragma unroll
            for (int r = 0; r < 4; ++r) { O1t[ft][r] *= al1; O2t[ft][r] *= al2; }
        }

        // ---- PV: O^T += V^T . P^T ----
        #pragma unroll
        for (int p = 0; p < 2; ++p) {
            #pragma unroll
            for (int ft = 0; ft < 8; ++ft) {
                const short8 va = *(const short8*)&Vs[16*ft + ln15][32*p + quad*8];
                O1t[ft] = __builtin_amdgcn_mfma_f32_16x16x32_bf16(va, p1f[p], O1t[ft], 0, 0, 0);
                O2t[ft] = __builtin_amdgcn_mfma_f32_16x16x32_bf16(va, p2f[p], O2t[ft], 0, 0, 0);
            }
        }
    }

    // ---- epilogue: out = x + O1/l1 - s2*O2/l2, layout [B][F][T] ----
    const float s2h = s2g[h];
    const float i1 = 1.f / l1;
    const float i2 = s2h / l2;

    const size_t obase = (size_t)b * F_DIM * T_DIM;
    const int f0 = h * HF;
    const int t = q0 + w * 16 + ln15;
    #pragma unroll
    for (int ft = 0; ft < 8; ++ft) {
        #pragma unroll
        for (int r = 0; r < 4; ++r) {
            const int feat = 16*ft + 4*quad + r;
            const size_t idx = obase + (size_t)(f0 + feat) * T_DIM + t;
            out[idx] = x[idx] + O1t[ft][r] * i1 - O2t[ft][r] * i2;
        }
    }
}

extern "C" void kernel_launch(void* const* d_in, const int* in_sizes, int n_in,
                              void* d_out, int out_size, void* d_ws, size_t ws_size,
                              hipStream_t stream)
{
    const float* x  = (const float*)d_in[0];
    const float* Wq = (const float*)d_in[1];
    const float* bq = (const float*)d_in[2];
    const float* Wk = (const float*)d_in[3];
    const float* bk = (const float*)d_in[4];
    const float* Wv = (const float*)d_in[5];
    const float* bv = (const float*)d_in[6];
    const float* s2 = (const float*)d_in[7];
    float* out = (float*)d_out;

    const size_t per = (size_t)B_DIM * T_DIM * F_DIM;  // 4M elems
    const size_t wsz = (size_t)F_DIM * F_DIM;          // 256K elems
    unsigned short* xt  = (unsigned short*)d_ws;
    unsigned short* Wqb = xt + per;
    unsigned short* Wkb = Wqb + wsz;
    unsigned short* Wvb = Wkb + wsz;
    unsigned short* Qb  = Wvb + wsz;
    unsigned short* Kb  = Qb + per;
    unsigned short* Vtb = Kb + per;   // total ~33.5 MB

    hipLaunchKernelGGL(prep_kernel, dim3(32, 8, 5), dim3(256), 0, stream,
                       x, Wq, Wk, Wv, xt, Wqb, Wkb, Wvb);

    hipLaunchKernelGGL(qk_gemm_rope_kernel, dim3(16, 8, 8), dim3(256), 0, stream,
                       xt, Wqb, Wkb, bq, bk, Qb, Kb);

    hipLaunchKernelGGL(vt_gemm_kernel, dim3(4, 32, 4), dim3(256), 0, stream,
                       xt, Wvb, bv, Vtb);

    hipLaunchKernelGGL(attn_mfma_kernel, dim3(32, 4, 4), dim3(256), 0, stream,
                       Qb, Kb, Vtb, x, s2, out);
}